// Round 7
// baseline (91.712 us; speedup 1.0000x reference)
//
#include <hip/hip_runtime.h>
#include <math.h>

#define BC 4
#define NODES 4096
#define FEAT 64
#define OUT_DIM 32
#define NWORDS (NODES / 32)        // 128 mask words per row
#define NEG_FILL (-1e16f)
#define MAXNBR 512                 // per-row neighbor cap (Binomial(131072,1/4096); P(>512)~0)

// ---------------------------------------------------------------------------
// Fused prep kernel, grid-partitioned:
//   blocks [0, zblocks):  z[b,n,:] = h[b,n,:] @ W   (float4-vectorized, 8 thr/row)
//   blocks [zblocks, ..): adjacency bitmask from COO (atomicOr dedupes, matching
//                         the reference's .at[r,c].set(1.0) semantics)
// ---------------------------------------------------------------------------
__global__ void prep(const float* __restrict__ h, const float* __restrict__ W,
                     const int* __restrict__ arow, const int* __restrict__ acol,
                     float* __restrict__ z, unsigned int* __restrict__ mask,
                     int n_edges, int zblocks) {
    if ((int)blockIdx.x < zblocks) {
        int t = blockIdx.x * 256 + threadIdx.x;   // < BC*NODES*8
        int g = t & 7;                            // which float4 of the out row
        int row = t >> 3;                         // b*NODES + n
        const float4* hr4 = (const float4*)(h + row * FEAT);  // 16 float4s
        const float4* W4 = (const float4*)W;      // W row f = 8 float4s
        float4 s = make_float4(0.f, 0.f, 0.f, 0.f);
#pragma unroll
        for (int fq = 0; fq < 16; ++fq) {
            float4 hv = hr4[fq];
            float4 w0 = W4[(fq * 4 + 0) * 8 + g];
            float4 w1 = W4[(fq * 4 + 1) * 8 + g];
            float4 w2 = W4[(fq * 4 + 2) * 8 + g];
            float4 w3 = W4[(fq * 4 + 3) * 8 + g];
            s.x = fmaf(hv.x, w0.x, s.x); s.y = fmaf(hv.x, w0.y, s.y);
            s.z = fmaf(hv.x, w0.z, s.z); s.w = fmaf(hv.x, w0.w, s.w);
            s.x = fmaf(hv.y, w1.x, s.x); s.y = fmaf(hv.y, w1.y, s.y);
            s.z = fmaf(hv.y, w1.z, s.z); s.w = fmaf(hv.y, w1.w, s.w);
            s.x = fmaf(hv.z, w2.x, s.x); s.y = fmaf(hv.z, w2.y, s.y);
            s.z = fmaf(hv.z, w2.z, s.z); s.w = fmaf(hv.z, w2.w, s.w);
            s.x = fmaf(hv.w, w3.x, s.x); s.y = fmaf(hv.w, w3.y, s.y);
            s.z = fmaf(hv.w, w3.z, s.z); s.w = fmaf(hv.w, w3.w, s.w);
        }
        ((float4*)z)[t] = s;
    } else {
        int t = ((int)blockIdx.x - zblocks) * 256 + threadIdx.x;
        if (t < n_edges) {
            int r = arow[t], c = acol[t];
            atomicOr(&mask[r * NWORDS + (c >> 5)], 1u << (c & 31));
        }
    }
}

// ---------------------------------------------------------------------------
// gatk v7 = v6 with (a) the 64-VGPR straitjacket removed and (b) single-pass
// row reuse.
//   - v6's launch_bounds(256,8) capped the allocator at 64 VGPR; tt[32]+state
//     is right at/over that -> probable silent spill (same failure class as
//     R4's scratch demotion, milder). Now (256,4): 128-VGPR cap, 16 waves/CU.
//   - rows loaded ONCE per chunk into vv[32] (lane=dim, coalesced); scores
//     via tt[j]=znl*vv[j] + one 31-shfl butterfly transpose (lane j <- s_j);
//     aggregation reuses vv with p broadcast by __shfl(p,j,32) -- pass-2
//     reloads and the ps[] LDS staging are GONE (L2 read traffic halved).
//   - all vv/tt indices compile-time -> stays in VGPRs (~85 live).
// ---------------------------------------------------------------------------
#define BFLYT(OFF)                                                  \
    do {                                                            \
        bool hi = (l & OFF) != 0;                                   \
        _Pragma("unroll")                                           \
        for (int i = 0; i < OFF; ++i) {                             \
            float send = hi ? tt[i] : tt[i + OFF];                  \
            float recv = __shfl_xor(send, OFF, 32);                 \
            float keep = hi ? tt[i + OFF] : tt[i];                  \
            tt[i] = keep + recv;                                    \
        }                                                           \
    } while (0)

__global__ __launch_bounds__(256, 4) void gatk(const float* __restrict__ z,
                                               const unsigned int* __restrict__ mask,
                                               float* __restrict__ out) {
    __shared__ unsigned short nbr[2][MAXNBR];
    __shared__ int totals[2];

    int wave = threadIdx.x >> 6;
    int lane = threadIdx.x & 63;
    int sub = lane >> 5;                   // half within wave
    int l = lane & 31;                     // lane within row == output dim
    int r = wave * 2 + sub;                // row slot 0..7
    int nloc = r >> 2;                     // which of the block's 2 nodes
    int b = r & 3;                         // batch
    int n = blockIdx.x * 2 + nloc;
    const float* zb = z + b * NODES * OUT_DIM;

    // ---- phase 1: neighbor compaction, once per node (waves 0/1) ----
    if (wave < 2) {
        int cn = blockIdx.x * 2 + wave;
        uint2 mw = ((const uint2*)(mask + cn * NWORDS))[lane];   // 2 words/lane
        int myc = __popc(mw.x) + __popc(mw.y);
        int pre = myc;
#pragma unroll
        for (int off = 1; off < 64; off <<= 1) {
            int t = __shfl_up(pre, off, 64);
            if (lane >= off) pre += t;
        }
        if (lane == 63) totals[wave] = pre;
        int posi = pre - myc;              // exclusive prefix = write offset
        unsigned short* mn = nbr[wave];
        unsigned int w; int cb = lane * 64;
        w = mw.x; while (w) { int bit = __ffs(w) - 1; w &= w - 1; mn[posi++] = (unsigned short)(cb + bit); }
        cb += 32;
        w = mw.y; while (w) { int bit = __ffs(w) - 1; w &= w - 1; mn[posi++] = (unsigned short)(cb + bit); }
    }
    float znl = zb[n * OUT_DIM + l];       // my dim of my node's row (coalesced)
    __syncthreads();

    int total = totals[nloc];
    const unsigned short* mn = nbr[nloc];

    float acc = 0.f;                       // lane=dim accumulator (ONE register)
    float lsum = 0.f;
    float m_run = -INFINITY;

    for (int base = 0; base < total; base += 32) {
        int lim = min(32, total - base);
        const unsigned short* mb = mn + base;

        // ---- coalesced row loads, kept in registers for reuse ----
        float vv[32];
#pragma unroll
        for (int j = 0; j < 32; ++j) {
            int mi = (j < lim) ? (int)mb[j] : 0;     // uniform LDS broadcast
            vv[j] = zb[mi * OUT_DIM + l];            // 128B coalesced / half-wave
        }

        // ---- scores: tt[j] = znl*vv[j]; butterfly => lane j holds s_j ----
        float tt[32];
#pragma unroll
        for (int j = 0; j < 32; ++j) tt[j] = znl * vv[j];
        BFLYT(16); BFLYT(8); BFLYT(4); BFLYT(2); BFLYT(1);
        float s = tt[0];
        s = (s >= 0.f) ? s : 0.1f * s;         // LeakyReLU(0.1)
        if (s == 0.f) s = NEG_FILL;            // masked_fill(att==0, -1e16)
        if (l >= lim) s = NEG_FILL;            // lane past end of list

        // ---- online softmax (lane = neighbor) ----
        float cmax = s;
#pragma unroll
        for (int off = 16; off > 0; off >>= 1)
            cmax = fmaxf(cmax, __shfl_xor(cmax, off, 32));
        float m_new = fmaxf(m_run, cmax);
        float alpha = (m_run == -INFINITY) ? 0.f : __expf(m_run - m_new);
        m_run = m_new;
        float p = __expf(s - m_new);           // bounded by 1; -1e16 -> 0
        float psum = p;
#pragma unroll
        for (int off = 16; off > 0; off >>= 1)
            psum += __shfl_xor(psum, off, 32);
        lsum = fmaf(lsum, alpha, psum);
        acc *= alpha;

        // ---- aggregation: reuse vv, broadcast p via shfl (no LDS, no reload) ----
        // invalid lanes (j>=lim): p==0 and vv[j] is row 0 -> contributes 0
#pragma unroll
        for (int j = 0; j < 32; ++j) {
            float pj = __shfl(p, j, 32);
            acc = fmaf(pj, vv[j], acc);
        }
    }

    float o;
    if (m_run <= -1e15f) {
        // degenerate row (all entries -1e16): reference softmax uniform over 4096
        float ssum = 0.f;
        for (int m2 = 0; m2 < NODES; ++m2)
            ssum += zb[m2 * OUT_DIM + l];
        o = ssum * (1.f / NODES);
    } else {
        o = acc / lsum;
    }
    out[((b << 12) | n) * OUT_DIM + l] = o;
}

// ---------------------------------------------------------------------------
extern "C" void kernel_launch(void* const* d_in, const int* in_sizes, int n_in,
                              void* d_out, int out_size, void* d_ws, size_t ws_size,
                              hipStream_t stream) {
    const float* h  = (const float*)d_in[0];
    const float* W  = (const float*)d_in[1];
    const int*   ar = (const int*)d_in[2];
    const int*   ac = (const int*)d_in[3];
    float* out = (float*)d_out;

    // ws layout: z (2 MB) | mask bitmap (2 MB)
    float* z = (float*)d_ws;
    unsigned int* mask =
        (unsigned int*)((char*)d_ws + (size_t)BC * NODES * OUT_DIM * sizeof(float));
    int n_edges = in_sizes[2];

    int zblocks = (BC * NODES * 8) / 256;          // 512
    int eblocks = (n_edges + 255) / 256;           // 512

    hipMemsetAsync(mask, 0, (size_t)NODES * NWORDS * sizeof(unsigned int), stream);
    prep<<<zblocks + eblocks, 256, 0, stream>>>(h, W, ar, ac, z, mask, n_edges, zblocks);
    gatk<<<NODES / 2, 256, 0, stream>>>(z, mask, out);
}